// Round 5
// baseline (144.243 us; speedup 1.0000x reference)
//
#include <hip/hip_runtime.h>
#include <hip/hip_bf16.h>

// CrossAttention fused pipeline, MI355X (gfx950)
// B=2, N=160, D=4096, H=4, DH=1024, SCALE=1/32 (applied twice)
//
// Stage 0: cvt x,y f32 -> bf16
// Stage 1+2: weight-stationary GEMM, NO vmcnt-coupled staging:
//   A fragments global->register (compiler-tracked waits), W f32->bf16 via
//   reg-staged dbuf LDS, raw s_barrier + lgkmcnt(0) only. BK=128, 32 steps.
//   grid (64 BN-panels, 2 z, 2 Mhalf) = 256 blocks = 1/CU.
//   Writes qT[b][d][n] (z=0, transposed) and k[320][4096] (z=1) directly.
// Stage 3: kkt = SCALE * k.k^T per (b,h)      (bf16)
// Stage 4: out = softplus(SCALE * qT @ kkt^T) (f32)

typedef __attribute__((ext_vector_type(4))) float  f32x4;
typedef __attribute__((ext_vector_type(8))) __bf16 bf16x8;
typedef __attribute__((ext_vector_type(4))) __bf16 bf16x4;

#define SCALE 0.03125f

static __device__ __forceinline__ f32x4 mfma16(bf16x8 a, bf16x8 b, f32x4 c) {
    return __builtin_amdgcn_mfma_f32_16x16x32_bf16(a, b, c, 0, 0, 0);
}

static __device__ __forceinline__ bf16x8 pack8(float4 a, float4 b) {
    bf16x8 r;
    r[0] = (__bf16)a.x; r[1] = (__bf16)a.y; r[2] = (__bf16)a.z; r[3] = (__bf16)a.w;
    r[4] = (__bf16)b.x; r[5] = (__bf16)b.y; r[6] = (__bf16)b.z; r[7] = (__bf16)b.w;
    return r;
}

static __device__ __forceinline__ float softplus(float x) {
    return fmaxf(x, 0.0f) + log1pf(expf(-fabsf(x)));
}

// ---------------------------------------------------------------------------
// Stage 0: f32 -> bf16 conversion of activations. grid (640, 2), 256 thr.
// ---------------------------------------------------------------------------
__global__ __launch_bounds__(256)
void cvt_kernel(const float* __restrict__ x, const float* __restrict__ y,
                __bf16* __restrict__ xb, __bf16* __restrict__ yb)
{
    const float* src = blockIdx.y ? y : x;
    __bf16* dst = blockIdx.y ? yb : xb;
    size_t i = ((size_t)blockIdx.x * 256 + threadIdx.x) * 8;
    float4 a = *(const float4*)(src + i);
    float4 b = *(const float4*)(src + i + 4);
    *(bf16x8*)(dst + i) = pack8(a, b);
}

// ---------------------------------------------------------------------------
// Stage 1+2: weight-stationary GEMM, register-direct A, LDS only for W.
// grid (64, 2, 2): x = N-panel (BN=64), y = z (0:q 1:k), z = M-half (batch).
// 256 threads = 4 waves (2M x 2N); wave tile 80 x 32; BK=128, 32 steps.
// Per step: 20 A-frag loads (global->reg, L2-hot), 8 W-frag ds_reads,
// 40 MFMA; W(s+1) ds_written from regs, W(s+2) loaded to regs.
// Barrier = lgkmcnt(0) + raw s_barrier: NO vmcnt drain in the loop.
// ---------------------------------------------------------------------------
__global__ __launch_bounds__(256, 1)
void qk_gemm(const __bf16* __restrict__ yb, const __bf16* __restrict__ xb,
             const float* __restrict__ Wq, const float* __restrict__ Wk,
             __bf16* __restrict__ qT, __bf16* __restrict__ kout)
{
    const int z  = blockIdx.y;            // 0: q (A=yb,W=Wq)  1: k (A=xb,W=Wk)
    const int mh = blockIdx.z;            // M half == batch index
    const __bf16* __restrict__ Ab = (z ? xb : yb) + (size_t)mh * 160 * 4096;
    const float*  __restrict__ W  = z ? Wk : Wq;
    const int bn = blockIdx.x * 64;

    __shared__ __bf16 lW[2][64 * 128];    // 16 KB per buffer

    const int tid  = threadIdx.x;
    const int lane = tid & 63;
    const int wid  = tid >> 6;
    const int wr   = wid >> 1;            // 0..1 : M group of 80
    const int wc   = wid & 1;             // 0..1 : N group of 32

    // ---- W staging coords: thread owns row jr, 32 consecutive f32 ----
    const int jr = tid >> 2;              // 0..63
    const int tk = (tid & 3) * 32;        // f32 k-offset within 128
    const float* wg = W + (size_t)(bn + jr) * 4096 + tk;
    // LDS slot layout: row j (256B), 16 slots of 16B; phys slot = s ^ (j&7)

    // ---- A fragment row pointers ----
    const int arow = wr * 80 + (lane & 15);
    const int akof = (lane >> 4) * 8;     // k sub-chunk
    const __bf16* apm[5];
    #pragma unroll
    for (int m = 0; m < 5; ++m)
        apm[m] = Ab + (size_t)(arow + m * 16) * 4096 + akof;

    f32x4 acc[5][2] = {};
    float4 wreg[8];

    // ---- prologue: W(0) -> LDS buf0; W(1) -> regs ----
    #pragma unroll
    for (int i = 0; i < 8; ++i) wreg[i] = *(const float4*)(wg + i * 4);
    #pragma unroll
    for (int i = 0; i < 4; ++i) {
        bf16x8 v = pack8(wreg[2 * i], wreg[2 * i + 1]);
        int sidx = (tid & 3) * 4 + i;
        *(bf16x8*)((char*)&lW[0][0] + jr * 256 + ((sidx ^ (jr & 7)) << 4)) = v;
    }
    #pragma unroll
    for (int i = 0; i < 8; ++i) wreg[i] = *(const float4*)(wg + 128 + i * 4);
    asm volatile("s_waitcnt lgkmcnt(0)" ::: "memory");
    __builtin_amdgcn_s_barrier();
    asm volatile("" ::: "memory");

    for (int s = 0; s < 32; ++s) {
        const int buf = s & 1;
        char* LB = (char*)&lW[buf][0];

        // A fragments for this step: 20 x bf16x8, straight from L2
        bf16x8 af[4][5];
        #pragma unroll
        for (int kk = 0; kk < 4; ++kk)
            #pragma unroll
            for (int m = 0; m < 5; ++m)
                af[kk][m] = *(const bf16x8*)(apm[m] + s * 128 + kk * 32);

        #pragma unroll
        for (int kk = 0; kk < 4; ++kk) {
            bf16x8 wf[2];
            #pragma unroll
            for (int jn = 0; jn < 2; ++jn) {
                int j    = wc * 32 + jn * 16 + (lane & 15);
                int slot = kk * 4 + (lane >> 4);
                wf[jn] = *(const bf16x8*)(LB + j * 256 + ((slot ^ (j & 7)) << 4));
            }
            __builtin_amdgcn_s_setprio(1);
            #pragma unroll
            for (int m = 0; m < 5; ++m) {
                acc[m][0] = mfma16(af[kk][m], wf[0], acc[m][0]);
                acc[m][1] = mfma16(af[kk][m], wf[1], acc[m][1]);
            }
            __builtin_amdgcn_s_setprio(0);
        }

        if (s < 31) {
            // stage W(s+1) from regs into the other buffer
            char* LN = (char*)&lW[buf ^ 1][0];
            #pragma unroll
            for (int i = 0; i < 4; ++i) {
                bf16x8 v = pack8(wreg[2 * i], wreg[2 * i + 1]);
                int sidx = (tid & 3) * 4 + i;
                *(bf16x8*)(LN + jr * 256 + ((sidx ^ (jr & 7)) << 4)) = v;
            }
            // prefetch W(s+2) into regs
            if (s < 30) {
                #pragma unroll
                for (int i = 0; i < 8; ++i)
                    wreg[i] = *(const float4*)(wg + (s + 2) * 128 + i * 4);
            }
            asm volatile("s_waitcnt lgkmcnt(0)" ::: "memory");
            __builtin_amdgcn_s_barrier();
            asm volatile("" ::: "memory");
        }
    }

    // Epilogue. C/D layout: col = lane&15, row = (lane>>4)*4 + r
    if (z == 0) {
        #pragma unroll
        for (int m = 0; m < 5; ++m) {
            const int row0 = wr * 80 + m * 16 + ((lane >> 4) << 2);  // 0..159
            #pragma unroll
            for (int jn = 0; jn < 2; ++jn) {
                const int col = bn + wc * 32 + jn * 16 + (lane & 15);
                bf16x4 v;
                #pragma unroll
                for (int r = 0; r < 4; ++r) v[r] = (__bf16)acc[m][jn][r];
                *(bf16x4*)(qT + (size_t)mh * 4096 * 160 + (size_t)col * 160 + row0) = v;
            }
        }
    } else {
        #pragma unroll
        for (int m = 0; m < 5; ++m) {
            const int row0 = mh * 160 + wr * 80 + m * 16 + ((lane >> 4) << 2);
            #pragma unroll
            for (int jn = 0; jn < 2; ++jn) {
                const int col = bn + wc * 32 + jn * 16 + (lane & 15);
                #pragma unroll
                for (int r = 0; r < 4; ++r)
                    kout[(size_t)(row0 + r) * 4096 + col] = (__bf16)acc[m][jn][r];
            }
        }
    }
}

// ---------------------------------------------------------------------------
// Stage 3: kkt (symmetric). One wave per 16x16 output tile, K=1024.
// ---------------------------------------------------------------------------
__global__ __launch_bounds__(64)
void kkt_kernel(const __bf16* __restrict__ kmat, __bf16* __restrict__ kkt)
{
    const int bh = blockIdx.x;            // b*4 + h
    const int b  = bh >> 2, h = bh & 3;
    const int i0 = blockIdx.y * 16;
    const int j0 = blockIdx.z * 16;
    const int lane = threadIdx.x;

    const __bf16* base = kmat + (size_t)b * 160 * 4096 + h * 1024;
    const int ko = (lane >> 4) << 3;
    const __bf16* pa = base + (size_t)(i0 + (lane & 15)) * 4096 + ko;
    const __bf16* pb = base + (size_t)(j0 + (lane & 15)) * 4096 + ko;

    f32x4 acc = {};
    #pragma unroll 4
    for (int kk = 0; kk < 1024; kk += 32) {
        bf16x8 a  = *(const bf16x8*)(pa + kk);
        bf16x8 bb = *(const bf16x8*)(pb + kk);
        acc = mfma16(a, bb, acc);
    }

    #pragma unroll
    for (int r = 0; r < 4; ++r) {
        int i = i0 + ((lane >> 4) << 2) + r;
        int j = j0 + (lane & 15);
        kkt[((size_t)bh * 160 + i) * 160 + j] = (__bf16)(acc[r] * SCALE);
    }
}

// ---------------------------------------------------------------------------
// Stage 4: dots + softplus. Per (b,h): C(4096x160) = qT[b] @ kkt[b,h]^T. K=160.
// ---------------------------------------------------------------------------
__global__ __launch_bounds__(256)
void dots_kernel(const __bf16* __restrict__ qT, const __bf16* __restrict__ kkt,
                 float* __restrict__ out)
{
    const int bh   = blockIdx.z;
    const int b    = bh >> 2;
    const int lane = threadIdx.x & 63;
    const int wid  = threadIdx.x >> 6;
    const int i0   = blockIdx.x * 64 + wid * 16;
    const int j0   = blockIdx.y * 32;

    const __bf16* Ab = qT + (size_t)b * 4096 * 160;
    const __bf16* Bb = kkt + (size_t)bh * 160 * 160;
    const int ko = (lane >> 4) << 3;
    const __bf16* pa  = Ab + (size_t)(i0 + (lane & 15)) * 160 + ko;
    const __bf16* pb0 = Bb + (size_t)(j0 + (lane & 15)) * 160 + ko;
    const __bf16* pb1 = pb0 + 16 * 160;

    f32x4 acc0 = {}, acc1 = {};
    #pragma unroll
    for (int m0 = 0; m0 < 160; m0 += 32) {
        bf16x8 a  = *(const bf16x8*)(pa + m0);
        bf16x8 b0 = *(const bf16x8*)(pb0 + m0);
        bf16x8 b1 = *(const bf16x8*)(pb1 + m0);
        acc0 = mfma16(a, b0, acc0);
        acc1 = mfma16(a, b1, acc1);
    }

    #pragma unroll
    for (int r = 0; r < 4; ++r) {
        int i = i0 + ((lane >> 4) << 2) + r;
        int j = j0 + (lane & 15);
        size_t o = ((size_t)bh * 4096 + i) * 160 + j;
        out[o]      = softplus(acc0[r] * SCALE);
        out[o + 16] = softplus(acc1[r] * SCALE);
    }
}

// ---------------------------------------------------------------------------
extern "C" void kernel_launch(void* const* d_in, const int* in_sizes, int n_in,
                              void* d_out, int out_size, void* d_ws, size_t ws_size,
                              hipStream_t stream)
{
    const float* x  = (const float*)d_in[0];
    const float* y  = (const float*)d_in[1];
    const float* Wq = (const float*)d_in[2];
    const float* Wk = (const float*)d_in[3];
    float* out = (float*)d_out;

    // ws layout (bf16): qT[2*4096*160], k[320*4096], kkt[8*160*160],
    //                   xb[320*4096], yb[320*4096]   (~10.9 MB)
    __bf16* qT  = (__bf16*)d_ws;
    __bf16* kbf = qT  + (size_t)2 * 4096 * 160;
    __bf16* kkt = kbf + (size_t)320 * 4096;
    __bf16* xb  = kkt + (size_t)8 * 160 * 160;
    __bf16* yb  = xb  + (size_t)320 * 4096;

    cvt_kernel <<<dim3(640, 2),    256, 0, stream>>>(x, y, xb, yb);
    qk_gemm    <<<dim3(64, 2, 2),  256, 0, stream>>>(yb, xb, Wq, Wk, qT, kbf);
    kkt_kernel <<<dim3(8, 10, 10),  64, 0, stream>>>(kbf, kkt);
    dots_kernel<<<dim3(64, 5, 8),  256, 0, stream>>>(qT, kkt, out);
}